// Round 4
// baseline (197.153 us; speedup 1.0000x reference)
//
#include <hip/hip_runtime.h>
#include <math.h>

#define BB 64

static __device__ __forceinline__ float relu_(float v){ return v > 0.f ? v : 0.f; }

// ---------- cost part: block handles bi = b*256+i; cost=min over 6, minout=min over j ----------
static __device__ void cost_body(const float* __restrict__ edges, float* __restrict__ cost,
                                 float* __restrict__ minout, int bi, float* red) {
    int j = threadIdx.x;
    const float* e = edges + ((size_t)bi * 256 + j) * 6;
    float m0 = e[0], m1 = e[1], m2 = e[2], m3 = e[3], m4 = e[4], m5 = e[5];
    cost[(size_t)bi * 256 + j] = fminf(fminf(fminf(m0, m1), fminf(m2, m3)), fminf(m4, m5));
    red[0*256+j]=m0; red[1*256+j]=m1; red[2*256+j]=m2;
    red[3*256+j]=m3; red[4*256+j]=m4; red[5*256+j]=m5;
    __syncthreads();
    for (int st = 128; st > 0; st >>= 1) {
        if (j < st) {
            #pragma unroll
            for (int q = 0; q < 6; ++q) red[q*256+j] = fminf(red[q*256+j], red[q*256+j+st]);
        }
        __syncthreads();
    }
    if (j < 6) minout[(size_t)bi * 6 + j] = red[j*256];
}

// ---------------- conv1 (3->16, VALID, k3) + avgpool2 + relu, box-sum trick ----------------
#define C1_BLOCKS 128
__global__ __launch_bounds__(256) void k_conv1(const float* __restrict__ x, const float* __restrict__ w,
        const float* __restrict__ bias, float* __restrict__ h1,
        const float* __restrict__ edges, float* __restrict__ cost, float* __restrict__ minout, int costBase) {
    __shared__ float sm[2210 + 6435 + 432 + 16]; // iBuf[34][65], T[3][33][65], sW, sB
    if ((int)blockIdx.x >= C1_BLOCKS) {
        int bi = costBase + (int)blockIdx.x - C1_BLOCKS;
        if (bi < BB * 256) cost_body(edges, cost, minout, bi, sm);
        return;
    }
    float* iBuf = sm; float* T = sm + 2210; float* sW = T + 6435; float* sB = sW + 432;
    int b = blockIdx.x >> 1, rg = blockIdx.x & 1;
    int t = threadIdx.x;
    int nyo = rg ? 15 : 16;
    int r0 = rg * 16, rowbase = rg * 32;
    int nrows = rg ? 32 : 34;
    for (int i = t; i < 432; i += 256) sW[i] = w[i];
    if (t < 16) sB[t] = bias[t];
    int na = 2 * nyo + 1;
    for (int ci = 0; ci < 3; ++ci) {
        __syncthreads();
        int tot = nrows * 64;
        for (int e = t; e < tot; e += 256) {
            int r = e >> 6, c = e & 63;
            iBuf[r * 65 + c] = x[(size_t)b * 12288 + ci * 4096 + (rowbase + r) * 64 + c] - 0.5f;
        }
        __syncthreads();
        int tot2 = na * 63;
        for (int e2 = t; e2 < tot2; e2 += 256) {
            int a = e2 / 63, c = e2 % 63;
            float* p = iBuf + a * 65 + c;
            T[ci * 2145 + a * 65 + c] = (p[0] + p[1]) + (p[65] + p[66]);
        }
    }
    __syncthreads();
    int npos = 31 * nyo;
    int p1 = t + 256;
    int yo0 = t / 31, xo0 = t % 31;
    bool v1 = p1 < npos;
    int yo1 = v1 ? p1 / 31 : 0, xo1 = v1 ? p1 % 31 : 0;
    float acc0[16], acc1[16];
    #pragma unroll
    for (int o = 0; o < 16; ++o) { acc0[o] = 0.f; acc1[o] = 0.f; }
    #pragma unroll 1
    for (int ci = 0; ci < 3; ++ci) {
        const float* T0 = T + ci * 2145 + yo0 * 130 + xo0 * 2;
        const float* T1 = T + ci * 2145 + yo1 * 130 + xo1 * 2;
        #pragma unroll
        for (int ky = 0; ky < 3; ++ky)
        #pragma unroll
        for (int kx = 0; kx < 3; ++kx) {
            float s0 = T0[ky * 65 + kx], s1 = T1[ky * 65 + kx];
            #pragma unroll
            for (int o = 0; o < 16; ++o) {
                float wv = sW[o * 27 + ci * 9 + ky * 3 + kx];
                acc0[o] += s0 * wv; acc1[o] += s1 * wv;
            }
        }
    }
    size_t ob = (size_t)b * 15376;
    #pragma unroll
    for (int o = 0; o < 16; ++o) {
        h1[ob + o * 961 + (r0 + yo0) * 31 + xo0] = relu_(0.25f * acc0[o] + sB[o]);
        if (v1) h1[ob + o * 961 + (r0 + yo1) * 31 + xo1] = relu_(0.25f * acc1[o] + sB[o]);
    }
}

// ---------------- conv2 (16->32, pad1, k3) + avgpool2 + relu, box-sum trick ----------------
#define C2_BLOCKS 256
__global__ __launch_bounds__(256) void k_conv2(const float* __restrict__ h1, const float* __restrict__ w,
        const float* __restrict__ bias, float* __restrict__ h2,
        const float* __restrict__ edges, float* __restrict__ cost, float* __restrict__ minout, int costBase) {
    __shared__ float sm[1024 + 16368 + 1152 + 8]; // iBuf[32][32], T[16][31][33], sW, sB
    if ((int)blockIdx.x >= C2_BLOCKS) {
        int bi = costBase + (int)blockIdx.x - C2_BLOCKS;
        if (bi < BB * 256) cost_body(edges, cost, minout, bi, sm);
        return;
    }
    float* iBuf = sm; float* T = sm + 1024; float* sW = T + 16368; float* sB = sW + 1152;
    int b = blockIdx.x >> 2, og = blockIdx.x & 3;
    int t = threadIdx.x;
    for (int i = t; i < 1152; i += 256) sW[i] = w[og * 1152 + i];
    if (t < 8) sB[t] = bias[og * 8 + t];
    for (int ci = 0; ci < 16; ++ci) {
        __syncthreads();
        for (int e = t; e < 1024; e += 256) {
            int r = e >> 5, c = e & 31;
            int iy = r - 1, ix = c - 1;
            float v = 0.f;
            if (iy >= 0 && iy < 31 && ix >= 0 && ix < 31)
                v = h1[(size_t)b * 15376 + ci * 961 + iy * 31 + ix];
            iBuf[e] = v;
        }
        __syncthreads();
        for (int e = t; e < 961; e += 256) {
            int a = e / 31, c = e % 31;
            float* p = iBuf + a * 32 + c;
            T[ci * 1023 + a * 33 + c] = (p[0] + p[1]) + (p[32] + p[33]);
        }
    }
    __syncthreads();
    if (t < 225) {
        int yo = t / 15, xo = t % 15;
        float acc[8];
        #pragma unroll
        for (int o = 0; o < 8; ++o) acc[o] = 0.f;
        #pragma unroll 1
        for (int ci = 0; ci < 16; ++ci) {
            const float* Tp = T + ci * 1023 + yo * 66 + xo * 2;
            #pragma unroll
            for (int ky = 0; ky < 3; ++ky)
            #pragma unroll
            for (int kx = 0; kx < 3; ++kx) {
                float s = Tp[ky * 33 + kx];
                #pragma unroll
                for (int o = 0; o < 8; ++o) acc[o] += s * sW[o * 144 + ci * 9 + ky * 3 + kx];
            }
        }
        size_t ob = (size_t)b * 7200 + (og * 8) * 225 + t;
        #pragma unroll
        for (int o = 0; o < 8; ++o) h2[ob + o * 225] = relu_(0.25f * acc[o] + sB[o]);
    }
}

// -------- conv3 (32->32, pad1, k3) + relu + venc (7200->8) + closest argmin, h3 stays in LDS --------
// 64 blocks x 1024 threads; og = tid>>8 computes 8 out-channels; h3s[32][225] in LDS.
__global__ __launch_bounds__(1024) void k_conv3ve(const float* __restrict__ h2, const float* __restrict__ w,
        const float* __restrict__ bias, const float* __restrict__ vew, const float* __restrict__ veb,
        const float* __restrict__ nodes, int* __restrict__ closest) {
    __shared__ float sIn[9248];            // padded input [32][17][17]
    __shared__ float sW[9216];             // full conv3 weights
    __shared__ float h3s[7200];            // [32][225]
    __shared__ float vred[1024];
    __shared__ float ve_s[8];
    __shared__ float val[256]; __shared__ int idx[256];
    int b = blockIdx.x; int tid = threadIdx.x;
    int og = tid >> 8, t = tid & 255;
    for (int e = tid; e < 9248; e += 1024) {
        int ci = e / 289, rem = e % 289;
        int r = rem / 17, c = rem % 17;
        int iy = r - 1, ix = c - 1;
        float v = 0.f;
        if (iy >= 0 && iy < 15 && ix >= 0 && ix < 15)
            v = h2[(size_t)b * 7200 + ci * 225 + iy * 15 + ix];
        sIn[e] = v;
    }
    for (int e = tid; e < 9216; e += 1024) sW[e] = w[e];
    __syncthreads();
    if (t < 225) {
        int yo = t / 15, xo = t % 15;
        float acc[8];
        #pragma unroll
        for (int o = 0; o < 8; ++o) acc[o] = 0.f;
        const float* Wg = sW + (og * 8) * 288;
        #pragma unroll 1
        for (int ci = 0; ci < 32; ++ci) {
            const float* Ip = sIn + ci * 289 + yo * 17 + xo;
            const float* Wp = Wg + ci * 9;
            #pragma unroll
            for (int ky = 0; ky < 3; ++ky)
            #pragma unroll
            for (int kx = 0; kx < 3; ++kx) {
                float iv = Ip[ky * 17 + kx];
                #pragma unroll
                for (int o = 0; o < 8; ++o) acc[o] += iv * Wp[o * 288 + ky * 3 + kx];
            }
        }
        #pragma unroll
        for (int o = 0; o < 8; ++o)
            h3s[(og * 8 + o) * 225 + t] = relu_(acc[o] + bias[og * 8 + o]);
    }
    __syncthreads();
    // venc: ve[f] = dot(h3s, vew[f]) + veb[f], f = tid>>7, 128 threads per f
    {
        int f = tid >> 7, i = tid & 127;
        const float* wf = vew + (size_t)f * 7200;
        float s = 0.f;
        for (int k = i; k < 7200; k += 128) s += h3s[k] * wf[k];
        vred[tid] = s; __syncthreads();
        for (int st = 64; st > 0; st >>= 1) {
            if (i < st) vred[tid] += vred[tid + st];
            __syncthreads();
        }
        if (i == 0) ve_s[f] = vred[tid] + veb[f];
        __syncthreads();
    }
    // closest = argmin_s ||ve - nodes[b,s]|| (tie -> lowest index)
    if (tid < 256) {
        const float* n = nodes + ((size_t)b * 256 + tid) * 8;
        float acc = 0.f;
        #pragma unroll
        for (int f = 0; f < 8; ++f) { float df = ve_s[f] - n[f]; acc += df * df; }
        val[tid] = acc; idx[tid] = tid;
    }
    __syncthreads();
    for (int st = 128; st > 0; st >>= 1) {
        if (tid < st) {
            float ov = val[tid + st]; int oi = idx[tid + st];
            if (ov < val[tid] || (ov == val[tid] && oi < idx[tid])) { val[tid] = ov; idx[tid] = oi; }
        }
        __syncthreads();
    }
    if (tid == 0) closest[b] = idx[0];
}

// ------- bellman (reg-resident cost) + tenc + topK + seq + transformer + MLP heads -------
// 64 blocks x 1024 threads. Thread (jg=tid>>8, t=tid&255) owns cost[jg*64+jj][t] in 64 VGPRs.
__global__ __launch_bounds__(1024, 4) void k_tail(
        const float* __restrict__ x, const int* __restrict__ closest,
        const float* __restrict__ cost, const float* __restrict__ nodes,
        const float* __restrict__ minout,
        const float* __restrict__ w1, const float* __restrict__ b1,
        const float* __restrict__ w2, const float* __restrict__ b2,
        const float* __restrict__ Wi, const float* __restrict__ bi_,
        const float* __restrict__ Wo, const float* __restrict__ bo,
        const float* __restrict__ g1, const float* __restrict__ be1,
        const float* __restrict__ g2, const float* __restrict__ be2,
        const float* __restrict__ W1, const float* __restrict__ bf1,
        const float* __restrict__ W2, const float* __restrict__ bf2,
        const float* __restrict__ H1, const float* __restrict__ hb1,
        const float* __restrict__ H2, const float* __restrict__ hb2,
        const float* __restrict__ H3, const float* __restrict__ hb3,
        float* __restrict__ out) {
    int b = blockIdx.x; int tid = threadIdx.x;
    int jg = tid >> 8, t = tid & 255;
    __shared__ __align__(16) float d_lds[256];
    __shared__ __align__(16) float part_b[1024];
    __shared__ float val[256]; __shared__ int idx[256]; __shared__ int sel[4];
    __shared__ float tc[3]; __shared__ float tt[64];
    __shared__ float sq[70], qkv[210], sc[25], tmp[70], f1[140], h2c[28];
    __shared__ __align__(16) float a1[512];
    __shared__ float parth[512]; __shared__ float a2[128];

    // ---- bellman ----
    int src = closest[b];
    const float* cb = cost + (size_t)b * 65536;
    float creg[64];
    #pragma unroll
    for (int jj = 0; jj < 64; ++jj)
        creg[jj] = cb[(size_t)((jg << 6) | jj) * 256 + t];
    float dv = 0.f;
    if (jg == 0) {
        dv = (t == src) ? 0.f : cb[(size_t)src * 256 + t];
        d_lds[t] = dv;
    }
    __syncthreads();
    for (int it = 0; it < 255; ++it) {
        float p = 3.402823466e+38f;
        const float4* d4 = (const float4*)(d_lds + (jg << 6));
        #pragma unroll
        for (int q = 0; q < 16; ++q) {
            float4 dd = d4[q];
            p = fminf(p, fminf(fminf(dd.x + creg[4*q+0], dd.y + creg[4*q+1]),
                               fminf(dd.z + creg[4*q+2], dd.w + creg[4*q+3])));
        }
        part_b[(jg << 8) | t] = p;
        __syncthreads();
        int ch = 0;
        if (jg == 0) {
            float m = fminf(fminf(part_b[t], part_b[256 + t]), fminf(part_b[512 + t], part_b[768 + t]));
            float nd = fminf(dv, m);
            ch = nd < dv;
            dv = nd;
            d_lds[t] = nd;
        }
        if (__syncthreads_count(ch) == 0) break;   // fixed point: further iterations identity
    }

    // ---- target encoder -> sq[0..13] ----
    if (tid < 3) tc[tid] = x[(size_t)b * 12288 + tid * 4096];
    __syncthreads();
    if (tid < 64) tt[tid] = relu_(b1[tid] + tc[0] * w1[tid * 3] + tc[1] * w1[tid * 3 + 1] + tc[2] * w1[tid * 3 + 2]);
    __syncthreads();
    if (tid < 14) {
        float e = b2[tid];
        for (int o = 0; o < 64; ++o) e += tt[o] * w2[tid * 64 + o];
        sq[tid] = e;
    }
    // ---- top-K(4) smallest spd (tie -> lowest index) ----
    float myv = 0.f;
    if (tid < 256) {
        float dvv = d_lds[tid];
        if (isinf(dvv)) dvv = 1e9f;
        myv = dvv;
    }
    for (int k = 0; k < 4; ++k) {
        if (tid < 256) { val[tid] = myv; idx[tid] = tid; }
        __syncthreads();
        for (int st = 128; st > 0; st >>= 1) {
            if (tid < st) {
                float ov = val[tid + st]; int oi = idx[tid + st];
                if (ov < val[tid] || (ov == val[tid] && oi < idx[tid])) { val[tid] = ov; idx[tid] = oi; }
            }
            __syncthreads();
        }
        if (tid == 0) sel[k] = idx[0];
        __syncthreads();
        if (tid < 256 && tid == sel[k]) myv = 3.402823466e+38f;
    }
    if (tid >= 64 && tid < 64 + 56) {
        int u = tid - 64; int k = u / 14; int c = u % 14; int id_ = sel[k];
        sq[(1 + k) * 14 + c] = (c < 8) ? nodes[((size_t)b * 256 + id_) * 8 + c]
                                       : minout[((size_t)b * 256 + id_) * 6 + (c - 8)];
    }
    __syncthreads();

    // ---- transformer block ----
    if (tid < 210) {
        int r = tid / 42, o = tid % 42; float v = bi_[o];
        for (int dd = 0; dd < 14; ++dd) v += sq[r * 14 + dd] * Wi[o * 14 + dd];
        qkv[tid] = v;
    }
    __syncthreads();
    if (tid < 25) {
        int r = tid / 5, c = tid % 5; float v = 0.f;
        for (int dd = 0; dd < 14; ++dd) v += qkv[r * 42 + dd] * qkv[c * 42 + 14 + dd];
        sc[tid] = v / sqrtf(14.0f);
    }
    __syncthreads();
    if (tid < 5) {
        float mx = sc[tid * 5];
        for (int c = 1; c < 5; ++c) mx = fmaxf(mx, sc[tid * 5 + c]);
        float e[5]; float sm = 0.f;
        for (int c = 0; c < 5; ++c) { e[c] = expf(sc[tid * 5 + c] - mx); sm += e[c]; }
        for (int c = 0; c < 5; ++c) sc[tid * 5 + c] = e[c] / sm;
    }
    __syncthreads();
    if (tid < 70) {
        int r = tid / 14, dd = tid % 14; float v = 0.f;
        for (int c = 0; c < 5; ++c) v += sc[r * 5 + c] * qkv[c * 42 + 28 + dd];
        tmp[tid] = v;
    }
    __syncthreads();
    if (tid < 70) {
        int r = tid / 14, o = tid % 14; float v = bo[o];
        for (int dd = 0; dd < 14; ++dd) v += tmp[r * 14 + dd] * Wo[o * 14 + dd];
        f1[tid] = sq[tid] + v;
    }
    __syncthreads();
    if (tid < 5) {                           // LN1
        float m = 0.f; for (int dd = 0; dd < 14; ++dd) m += f1[tid * 14 + dd]; m /= 14.f;
        float v = 0.f; for (int dd = 0; dd < 14; ++dd) { float z = f1[tid * 14 + dd] - m; v += z * z; } v /= 14.f;
        float inv = 1.f / sqrtf(v + 1e-5f);
        for (int dd = 0; dd < 14; ++dd) sq[tid * 14 + dd] = (f1[tid * 14 + dd] - m) * inv * g1[dd] + be1[dd];
    }
    __syncthreads();
    if (tid < 140) {
        int r = tid / 28, o = tid % 28; float v = bf1[o];
        for (int dd = 0; dd < 14; ++dd) v += sq[r * 14 + dd] * W1[o * 14 + dd];
        f1[tid] = relu_(v);
    }
    __syncthreads();
    if (tid < 70) {
        int r = tid / 14, o = tid % 14; float v = bf2[o];
        for (int i = 0; i < 28; ++i) v += f1[r * 28 + i] * W2[o * 28 + i];
        tmp[tid] = sq[tid] + v;
    }
    __syncthreads();
    if (tid < 5) {                           // LN2
        float m = 0.f; for (int dd = 0; dd < 14; ++dd) m += tmp[tid * 14 + dd]; m /= 14.f;
        float v = 0.f; for (int dd = 0; dd < 14; ++dd) { float z = tmp[tid * 14 + dd] - m; v += z * z; } v /= 14.f;
        float inv = 1.f / sqrtf(v + 1e-5f);
        for (int dd = 0; dd < 14; ++dd) sq[tid * 14 + dd] = (tmp[tid * 14 + dd] - m) * inv * g2[dd] + be2[dd];
    }
    __syncthreads();
    if (tid < 28) {
        int c = tid - 14;
        h2c[tid] = (tid < 14) ? sq[tid]
                              : 0.25f * (sq[14 + c] + sq[28 + c] + sq[42 + c] + sq[56 + c]);
    }
    __syncthreads();
    if (tid < 512) {   // head1: 28 -> 512, one output per thread
        int o = tid;
        const float4* Hr = (const float4*)(H1 + o * 28);
        float v = hb1[o];
        #pragma unroll
        for (int i = 0; i < 7; ++i) {
            float4 h4 = Hr[i];
            v += h4.x * h2c[i*4] + h4.y * h2c[i*4+1] + h4.z * h2c[i*4+2] + h4.w * h2c[i*4+3];
        }
        a1[o] = relu_(v);
    }
    __syncthreads();
    if (tid < 512) {   // head2: 512 -> 128, dot split over 4 threads
        int o = tid & 127, q = tid >> 7;
        const float4* Hr = (const float4*)(H2 + o * 512 + q * 128);
        const float* ap = a1 + q * 128;
        float v = 0.f;
        #pragma unroll
        for (int i = 0; i < 32; ++i) {
            float4 h4 = Hr[i];
            v += h4.x * ap[i*4] + h4.y * ap[i*4+1] + h4.z * ap[i*4+2] + h4.w * ap[i*4+3];
        }
        parth[tid] = v;
    }
    __syncthreads();
    if (tid < 128) a2[tid] = relu_(hb2[tid] + parth[tid] + parth[tid + 128] + parth[tid + 256] + parth[tid + 384]);
    __syncthreads();
    if (tid < 6) {
        const float4* Hr = (const float4*)(H3 + tid * 128);
        float v = hb3[tid];
        for (int i = 0; i < 32; ++i) {
            float4 h4 = Hr[i];
            v += h4.x * a2[i*4] + h4.y * a2[i*4+1] + h4.z * a2[i*4+2] + h4.w * a2[i*4+3];
        }
        out[b * 6 + tid] = v;
    }
}

extern "C" void kernel_launch(void* const* d_in, const int* in_sizes, int n_in,
                              void* d_out, int out_size, void* d_ws, size_t ws_size,
                              hipStream_t stream) {
    const float* x   = (const float*)d_in[0];
    const float* c1w = (const float*)d_in[1];
    const float* c1b = (const float*)d_in[2];
    const float* c2w = (const float*)d_in[3];
    const float* c2b = (const float*)d_in[4];
    const float* c3w = (const float*)d_in[5];
    const float* c3b = (const float*)d_in[6];
    const float* vew = (const float*)d_in[7];
    const float* veb = (const float*)d_in[8];
    const float* t1w = (const float*)d_in[9];
    const float* t1b = (const float*)d_in[10];
    const float* t2w = (const float*)d_in[11];
    const float* t2b = (const float*)d_in[12];
    const float* aiw = (const float*)d_in[13];
    const float* aib = (const float*)d_in[14];
    const float* aow = (const float*)d_in[15];
    const float* aob = (const float*)d_in[16];
    const float* l1g = (const float*)d_in[17];
    const float* l1bb= (const float*)d_in[18];
    const float* l2g = (const float*)d_in[19];
    const float* l2bb= (const float*)d_in[20];
    const float* f1w = (const float*)d_in[21];
    const float* f1b = (const float*)d_in[22];
    const float* f2w = (const float*)d_in[23];
    const float* f2b = (const float*)d_in[24];
    const float* h1w = (const float*)d_in[25];
    const float* h1b = (const float*)d_in[26];
    const float* h2w = (const float*)d_in[27];
    const float* h2b = (const float*)d_in[28];
    const float* h3w = (const float*)d_in[29];
    const float* h3b = (const float*)d_in[30];
    const float* nodes = (const float*)d_in[31];
    const float* edges = (const float*)d_in[32];

    float* W = (float*)d_ws;
    int*   closest = (int*)(W + 512);  // 64
    float* h1     = W + 32768;         // 984064
    float* h2     = W + 1016832;       // 460800
    float* minout = W + 1938432;       // 98304
    float* cost   = W + 2097152;       // 4194304

    // cost pass (16384 blocks) split across the two conv kernels as grid appendices
    const int nc1 = 8192, nc2 = 8192;
    k_conv1<<<C1_BLOCKS + nc1, 256, 0, stream>>>(x, c1w, c1b, h1, edges, cost, minout, 0);
    k_conv2<<<C2_BLOCKS + nc2, 256, 0, stream>>>(h1, c2w, c2b, h2, edges, cost, minout, nc1);
    k_conv3ve<<<BB, 1024, 0, stream>>>(h2, c3w, c3b, vew, veb, nodes, closest);
    k_tail<<<BB, 1024, 0, stream>>>(x, closest, cost, nodes, minout,
                                    t1w, t1b, t2w, t2b,
                                    aiw, aib, aow, aob, l1g, l1bb, l2g, l2bb,
                                    f1w, f1b, f2w, f2b, h1w, h1b, h2w, h2b, h3w, h3b,
                                    (float*)d_out);
}

// Round 5
// 147.061 us; speedup vs baseline: 1.3406x; 1.3406x over previous
//
#include <hip/hip_runtime.h>
#include <math.h>

#define BB 64

static __device__ __forceinline__ float relu_(float v){ return v > 0.f ? v : 0.f; }

// ---------- cost part: block handles bi = b*256+i; cost=min over 6, minout=min over j ----------
static __device__ void cost_body(const float* __restrict__ edges, float* __restrict__ cost,
                                 float* __restrict__ minout, int bi, float* red) {
    int j = threadIdx.x;
    const float* e = edges + ((size_t)bi * 256 + j) * 6;
    float m0 = e[0], m1 = e[1], m2 = e[2], m3 = e[3], m4 = e[4], m5 = e[5];
    cost[(size_t)bi * 256 + j] = fminf(fminf(fminf(m0, m1), fminf(m2, m3)), fminf(m4, m5));
    red[0*256+j]=m0; red[1*256+j]=m1; red[2*256+j]=m2;
    red[3*256+j]=m3; red[4*256+j]=m4; red[5*256+j]=m5;
    __syncthreads();
    for (int st = 128; st > 0; st >>= 1) {
        if (j < st) {
            #pragma unroll
            for (int q = 0; q < 6; ++q) red[q*256+j] = fminf(red[q*256+j], red[q*256+j+st]);
        }
        __syncthreads();
    }
    if (j < 6) minout[(size_t)bi * 6 + j] = red[j*256];
}

// ---------------- conv1 (3->16, VALID, k3) + avgpool2 + relu, box-sum + scalar weights ----------------
#define C1_BLOCKS 128
__global__ __launch_bounds__(256) void k_conv1(const float* __restrict__ x, const float* __restrict__ w,
        const float* __restrict__ bias, float* __restrict__ h1,
        const float* __restrict__ edges, float* __restrict__ cost, float* __restrict__ minout, int costBase) {
    __shared__ float sm[2210 + 6435]; // iBuf[34][65], T[3][33][65]
    if ((int)blockIdx.x >= C1_BLOCKS) {
        int bi = costBase + (int)blockIdx.x - C1_BLOCKS;
        if (bi < BB * 256) cost_body(edges, cost, minout, bi, sm);
        return;
    }
    float* iBuf = sm; float* T = sm + 2210;
    int b = blockIdx.x >> 1, rg = blockIdx.x & 1;
    int t = threadIdx.x;
    int nyo = rg ? 15 : 16;
    int r0 = rg * 16, rowbase = rg * 32;
    int nrows = rg ? 32 : 34;
    int na = 2 * nyo + 1;
    for (int ci = 0; ci < 3; ++ci) {
        __syncthreads();
        int tot = nrows * 64;
        for (int e = t; e < tot; e += 256) {
            int r = e >> 6, c = e & 63;
            iBuf[r * 65 + c] = x[(size_t)b * 12288 + ci * 4096 + (rowbase + r) * 64 + c] - 0.5f;
        }
        __syncthreads();
        int tot2 = na * 63;
        for (int e2 = t; e2 < tot2; e2 += 256) {
            int a = e2 / 63, c = e2 % 63;
            float* p = iBuf + a * 65 + c;
            T[ci * 2145 + a * 65 + c] = (p[0] + p[1]) + (p[65] + p[66]);
        }
    }
    __syncthreads();
    int npos = 31 * nyo;
    int p1 = t + 256;
    int yo0 = t / 31, xo0 = t % 31;
    bool v1 = p1 < npos;
    int yo1 = v1 ? p1 / 31 : 0, xo1 = v1 ? p1 % 31 : 0;
    float acc0[16], acc1[16];
    #pragma unroll
    for (int o = 0; o < 16; ++o) { acc0[o] = 0.f; acc1[o] = 0.f; }
    #pragma unroll 1
    for (int ci = 0; ci < 3; ++ci) {
        const float* T0 = T + ci * 2145 + yo0 * 130 + xo0 * 2;
        const float* T1 = T + ci * 2145 + yo1 * 130 + xo1 * 2;
        float s0[9], s1[9];
        #pragma unroll
        for (int ky = 0; ky < 3; ++ky)
        #pragma unroll
        for (int kx = 0; kx < 3; ++kx) { s0[ky*3+kx] = T0[ky * 65 + kx]; s1[ky*3+kx] = T1[ky * 65 + kx]; }
        #pragma unroll
        for (int o = 0; o < 16; ++o) {
            const float* Wp = w + o * 27 + ci * 9;   // uniform -> s_load
            #pragma unroll
            for (int k = 0; k < 9; ++k) { float wv = Wp[k]; acc0[o] += s0[k] * wv; acc1[o] += s1[k] * wv; }
        }
    }
    size_t ob = (size_t)b * 15376;
    #pragma unroll
    for (int o = 0; o < 16; ++o) {
        float bo_ = bias[o];
        h1[ob + o * 961 + (r0 + yo0) * 31 + xo0] = relu_(0.25f * acc0[o] + bo_);
        if (v1) h1[ob + o * 961 + (r0 + yo1) * 31 + xo1] = relu_(0.25f * acc1[o] + bo_);
    }
}

// ---------------- conv2 (16->32, pad1, k3) + avgpool2 + relu, box-sum + scalar weights ----------------
#define C2_BLOCKS 256
__global__ __launch_bounds__(256) void k_conv2(const float* __restrict__ h1, const float* __restrict__ w,
        const float* __restrict__ bias, float* __restrict__ h2,
        const float* __restrict__ edges, float* __restrict__ cost, float* __restrict__ minout, int costBase) {
    __shared__ float sm[1024 + 16368]; // iBuf[32][32], T[16][31][33]
    if ((int)blockIdx.x >= C2_BLOCKS) {
        int bi = costBase + (int)blockIdx.x - C2_BLOCKS;
        if (bi < BB * 256) cost_body(edges, cost, minout, bi, sm);
        return;
    }
    float* iBuf = sm; float* T = sm + 1024;
    int b = blockIdx.x >> 2, og = blockIdx.x & 3;
    int t = threadIdx.x;
    for (int ci = 0; ci < 16; ++ci) {
        __syncthreads();
        for (int e = t; e < 1024; e += 256) {
            int r = e >> 5, c = e & 31;
            int iy = r - 1, ix = c - 1;
            float v = 0.f;
            if (iy >= 0 && iy < 31 && ix >= 0 && ix < 31)
                v = h1[(size_t)b * 15376 + ci * 961 + iy * 31 + ix];
            iBuf[e] = v;
        }
        __syncthreads();
        for (int e = t; e < 961; e += 256) {
            int a = e / 31, c = e % 31;
            float* p = iBuf + a * 32 + c;
            T[ci * 1023 + a * 33 + c] = (p[0] + p[1]) + (p[32] + p[33]);
        }
    }
    __syncthreads();
    if (t < 225) {
        int yo = t / 15, xo = t % 15;
        float acc[8];
        #pragma unroll
        for (int o = 0; o < 8; ++o) acc[o] = 0.f;
        const float* Wg = w + og * 1152;
        #pragma unroll 1
        for (int ci = 0; ci < 16; ++ci) {
            const float* Tp = T + ci * 1023 + yo * 66 + xo * 2;
            float tv[9];
            #pragma unroll
            for (int ky = 0; ky < 3; ++ky)
            #pragma unroll
            for (int kx = 0; kx < 3; ++kx) tv[ky*3+kx] = Tp[ky * 33 + kx];
            #pragma unroll
            for (int o = 0; o < 8; ++o) {
                const float* Wp = Wg + o * 144 + ci * 9;   // uniform -> s_load
                #pragma unroll
                for (int k = 0; k < 9; ++k) acc[o] += tv[k] * Wp[k];
            }
        }
        size_t ob = (size_t)b * 7200 + (og * 8) * 225 + t;
        #pragma unroll
        for (int o = 0; o < 8; ++o) h2[ob + o * 225] = relu_(0.25f * acc[o] + bias[og * 8 + o]);
    }
}

// ---------------- conv3 (32->32, pad1, k3) + relu, scalar weights ----------------
#define C3_BLOCKS 256
__global__ __launch_bounds__(256) void k_conv3(const float* __restrict__ h2, const float* __restrict__ w,
        const float* __restrict__ bias, float* __restrict__ h3,
        const float* __restrict__ edges, float* __restrict__ cost, float* __restrict__ minout, int costBase) {
    __shared__ float sm[9248];  // sIn[32][17][17]
    if ((int)blockIdx.x >= C3_BLOCKS) {
        int bi = costBase + (int)blockIdx.x - C3_BLOCKS;
        if (bi < BB * 256) cost_body(edges, cost, minout, bi, sm);
        return;
    }
    float* sIn = sm;
    int b = blockIdx.x >> 2, og = blockIdx.x & 3;
    int t = threadIdx.x;
    for (int e = t; e < 9248; e += 256) {
        int ci = e / 289, rem = e % 289;
        int r = rem / 17, c = rem % 17;
        int iy = r - 1, ix = c - 1;
        float v = 0.f;
        if (iy >= 0 && iy < 15 && ix >= 0 && ix < 15)
            v = h2[(size_t)b * 7200 + ci * 225 + iy * 15 + ix];
        sIn[e] = v;
    }
    __syncthreads();
    if (t < 225) {
        int yo = t / 15, xo = t % 15;
        float acc[8];
        #pragma unroll
        for (int o = 0; o < 8; ++o) acc[o] = 0.f;
        const float* Wg = w + og * 2304;
        #pragma unroll 1
        for (int ci = 0; ci < 32; ++ci) {
            const float* Ip = sIn + ci * 289 + yo * 17 + xo;
            float iv[9];
            #pragma unroll
            for (int ky = 0; ky < 3; ++ky)
            #pragma unroll
            for (int kx = 0; kx < 3; ++kx) iv[ky*3+kx] = Ip[ky * 17 + kx];
            #pragma unroll
            for (int o = 0; o < 8; ++o) {
                const float* Wp = Wg + o * 288 + ci * 9;   // uniform -> s_load
                #pragma unroll
                for (int k = 0; k < 9; ++k) acc[o] += iv[k] * Wp[k];
            }
        }
        size_t ob = (size_t)b * 7200 + (og * 8) * 225 + t;
        #pragma unroll
        for (int o = 0; o < 8; ++o) h3[ob + o * 225] = relu_(acc[o] + bias[og * 8 + o]);
    }
}

// ------- venc + closest + bellman (reg-resident cost) + tenc + topK + seq + transformer + heads -------
// 64 blocks x 1024 threads. Thread (jg=tid>>8, t=tid&255) owns cost[jg*64+jj][t] in 64 VGPRs.
__global__ __launch_bounds__(1024, 4) void k_tail(
        const float* __restrict__ x, const float* __restrict__ h3,
        const float* __restrict__ vew, const float* __restrict__ veb,
        const float* __restrict__ cost, const float* __restrict__ nodes,
        const float* __restrict__ minout,
        const float* __restrict__ w1, const float* __restrict__ b1,
        const float* __restrict__ w2, const float* __restrict__ b2,
        const float* __restrict__ Wi, const float* __restrict__ bi_,
        const float* __restrict__ Wo, const float* __restrict__ bo,
        const float* __restrict__ g1, const float* __restrict__ be1,
        const float* __restrict__ g2, const float* __restrict__ be2,
        const float* __restrict__ W1, const float* __restrict__ bf1,
        const float* __restrict__ W2, const float* __restrict__ bf2,
        const float* __restrict__ H1, const float* __restrict__ hb1,
        const float* __restrict__ H2, const float* __restrict__ hb2,
        const float* __restrict__ H3, const float* __restrict__ hb3,
        float* __restrict__ out) {
    int b = blockIdx.x; int tid = threadIdx.x;
    int jg = tid >> 8, t = tid & 255;
    __shared__ __align__(16) float d_lds[256];
    __shared__ __align__(16) float part_b[1024];
    __shared__ float ve_s[8]; __shared__ int ssrc;
    __shared__ float val[256]; __shared__ int idx[256]; __shared__ int sel[4];
    __shared__ float tc[3]; __shared__ float tt[64];
    __shared__ float sq[70], qkv[210], sc[25], tmp[70], f1[140], h2c[28];
    __shared__ __align__(16) float a1[512];
    __shared__ float parth[512]; __shared__ float a2[128];

    // ---- venc: ve[f] = dot(h3[b], vew[f]) + veb[f]; 128 threads per f ----
    {
        int f = tid >> 7, i = tid & 127;
        const float* hb = h3 + (size_t)b * 7200;
        const float* wf = vew + (size_t)f * 7200;
        float s = 0.f;
        for (int k = i; k < 7200; k += 128) s += hb[k] * wf[k];
        part_b[tid] = s; __syncthreads();
        for (int st = 64; st > 0; st >>= 1) {
            if (i < st) part_b[tid] += part_b[tid + st];
            __syncthreads();
        }
        if (i == 0) ve_s[f] = part_b[tid] + veb[f];
        __syncthreads();
    }
    // ---- closest = argmin_s ||ve - nodes[b,s]|| (tie -> lowest index) ----
    if (tid < 256) {
        const float* n = nodes + ((size_t)b * 256 + tid) * 8;
        float acc = 0.f;
        #pragma unroll
        for (int f = 0; f < 8; ++f) { float df = ve_s[f] - n[f]; acc += df * df; }
        val[tid] = acc; idx[tid] = tid;
    }
    __syncthreads();
    for (int st = 128; st > 0; st >>= 1) {
        if (tid < st) {
            float ov = val[tid + st]; int oi = idx[tid + st];
            if (ov < val[tid] || (ov == val[tid] && oi < idx[tid])) { val[tid] = ov; idx[tid] = oi; }
        }
        __syncthreads();
    }
    if (tid == 0) ssrc = idx[0];
    __syncthreads();
    int src = ssrc;

    // ---- bellman ----
    const float* cb = cost + (size_t)b * 65536;
    float creg[64];
    #pragma unroll
    for (int jj = 0; jj < 64; ++jj)
        creg[jj] = cb[(size_t)((jg << 6) | jj) * 256 + t];
    float dv = 0.f;
    if (jg == 0) {
        dv = (t == src) ? 0.f : cb[(size_t)src * 256 + t];
        d_lds[t] = dv;
    }
    __syncthreads();
    for (int it = 0; it < 255; ++it) {
        float p = 3.402823466e+38f;
        const float4* d4 = (const float4*)(d_lds + (jg << 6));
        #pragma unroll
        for (int q = 0; q < 16; ++q) {
            float4 dd = d4[q];
            p = fminf(p, fminf(fminf(dd.x + creg[4*q+0], dd.y + creg[4*q+1]),
                               fminf(dd.z + creg[4*q+2], dd.w + creg[4*q+3])));
        }
        part_b[(jg << 8) | t] = p;
        __syncthreads();
        int ch = 0;
        if (jg == 0) {
            float m = fminf(fminf(part_b[t], part_b[256 + t]), fminf(part_b[512 + t], part_b[768 + t]));
            float nd = fminf(dv, m);
            ch = nd < dv;
            dv = nd;
            d_lds[t] = nd;
        }
        if (__syncthreads_count(ch) == 0) break;   // fixed point: further iterations identity
    }

    // ---- target encoder -> sq[0..13] ----
    if (tid < 3) tc[tid] = x[(size_t)b * 12288 + tid * 4096];
    __syncthreads();
    if (tid < 64) tt[tid] = relu_(b1[tid] + tc[0] * w1[tid * 3] + tc[1] * w1[tid * 3 + 1] + tc[2] * w1[tid * 3 + 2]);
    __syncthreads();
    if (tid < 14) {
        float e = b2[tid];
        for (int o = 0; o < 64; ++o) e += tt[o] * w2[tid * 64 + o];
        sq[tid] = e;
    }
    // ---- top-K(4) smallest spd (tie -> lowest index) ----
    float myv = 0.f;
    if (tid < 256) {
        float dvv = d_lds[tid];
        if (isinf(dvv)) dvv = 1e9f;
        myv = dvv;
    }
    for (int k = 0; k < 4; ++k) {
        if (tid < 256) { val[tid] = myv; idx[tid] = tid; }
        __syncthreads();
        for (int st = 128; st > 0; st >>= 1) {
            if (tid < st) {
                float ov = val[tid + st]; int oi = idx[tid + st];
                if (ov < val[tid] || (ov == val[tid] && oi < idx[tid])) { val[tid] = ov; idx[tid] = oi; }
            }
            __syncthreads();
        }
        if (tid == 0) sel[k] = idx[0];
        __syncthreads();
        if (tid < 256 && tid == sel[k]) myv = 3.402823466e+38f;
    }
    if (tid >= 64 && tid < 64 + 56) {
        int u = tid - 64; int k = u / 14; int c = u % 14; int id_ = sel[k];
        sq[(1 + k) * 14 + c] = (c < 8) ? nodes[((size_t)b * 256 + id_) * 8 + c]
                                       : minout[((size_t)b * 256 + id_) * 6 + (c - 8)];
    }
    __syncthreads();

    // ---- transformer block ----
    if (tid < 210) {
        int r = tid / 42, o = tid % 42; float v = bi_[o];
        for (int dd = 0; dd < 14; ++dd) v += sq[r * 14 + dd] * Wi[o * 14 + dd];
        qkv[tid] = v;
    }
    __syncthreads();
    if (tid < 25) {
        int r = tid / 5, c = tid % 5; float v = 0.f;
        for (int dd = 0; dd < 14; ++dd) v += qkv[r * 42 + dd] * qkv[c * 42 + 14 + dd];
        sc[tid] = v / sqrtf(14.0f);
    }
    __syncthreads();
    if (tid < 5) {
        float mx = sc[tid * 5];
        for (int c = 1; c < 5; ++c) mx = fmaxf(mx, sc[tid * 5 + c]);
        float e[5]; float sm = 0.f;
        for (int c = 0; c < 5; ++c) { e[c] = expf(sc[tid * 5 + c] - mx); sm += e[c]; }
        for (int c = 0; c < 5; ++c) sc[tid * 5 + c] = e[c] / sm;
    }
    __syncthreads();
    if (tid < 70) {
        int r = tid / 14, dd = tid % 14; float v = 0.f;
        for (int c = 0; c < 5; ++c) v += sc[r * 5 + c] * qkv[c * 42 + 28 + dd];
        tmp[tid] = v;
    }
    __syncthreads();
    if (tid < 70) {
        int r = tid / 14, o = tid % 14; float v = bo[o];
        for (int dd = 0; dd < 14; ++dd) v += tmp[r * 14 + dd] * Wo[o * 14 + dd];
        f1[tid] = sq[tid] + v;
    }
    __syncthreads();
    if (tid < 5) {                           // LN1
        float m = 0.f; for (int dd = 0; dd < 14; ++dd) m += f1[tid * 14 + dd]; m /= 14.f;
        float v = 0.f; for (int dd = 0; dd < 14; ++dd) { float z = f1[tid * 14 + dd] - m; v += z * z; } v /= 14.f;
        float inv = 1.f / sqrtf(v + 1e-5f);
        for (int dd = 0; dd < 14; ++dd) sq[tid * 14 + dd] = (f1[tid * 14 + dd] - m) * inv * g1[dd] + be1[dd];
    }
    __syncthreads();
    if (tid < 140) {
        int r = tid / 28, o = tid % 28; float v = bf1[o];
        for (int dd = 0; dd < 14; ++dd) v += sq[r * 14 + dd] * W1[o * 14 + dd];
        f1[tid] = relu_(v);
    }
    __syncthreads();
    if (tid < 70) {
        int r = tid / 14, o = tid % 14; float v = bf2[o];
        for (int i = 0; i < 28; ++i) v += f1[r * 28 + i] * W2[o * 28 + i];
        tmp[tid] = sq[tid] + v;
    }
    __syncthreads();
    if (tid < 5) {                           // LN2
        float m = 0.f; for (int dd = 0; dd < 14; ++dd) m += tmp[tid * 14 + dd]; m /= 14.f;
        float v = 0.f; for (int dd = 0; dd < 14; ++dd) { float z = tmp[tid * 14 + dd] - m; v += z * z; } v /= 14.f;
        float inv = 1.f / sqrtf(v + 1e-5f);
        for (int dd = 0; dd < 14; ++dd) sq[tid * 14 + dd] = (tmp[tid * 14 + dd] - m) * inv * g2[dd] + be2[dd];
    }
    __syncthreads();
    if (tid < 28) {
        int c = tid - 14;
        h2c[tid] = (tid < 14) ? sq[tid]
                              : 0.25f * (sq[14 + c] + sq[28 + c] + sq[42 + c] + sq[56 + c]);
    }
    __syncthreads();
    if (tid < 512) {   // head1: 28 -> 512, one output per thread
        int o = tid;
        const float4* Hr = (const float4*)(H1 + o * 28);
        float v = hb1[o];
        #pragma unroll
        for (int i = 0; i < 7; ++i) {
            float4 h4 = Hr[i];
            v += h4.x * h2c[i*4] + h4.y * h2c[i*4+1] + h4.z * h2c[i*4+2] + h4.w * h2c[i*4+3];
        }
        a1[o] = relu_(v);
    }
    __syncthreads();
    if (tid < 512) {   // head2: 512 -> 128, dot split over 4 threads
        int o = tid & 127, q = tid >> 7;
        const float4* Hr = (const float4*)(H2 + o * 512 + q * 128);
        const float* ap = a1 + q * 128;
        float v = 0.f;
        #pragma unroll
        for (int i = 0; i < 32; ++i) {
            float4 h4 = Hr[i];
            v += h4.x * ap[i*4] + h4.y * ap[i*4+1] + h4.z * ap[i*4+2] + h4.w * ap[i*4+3];
        }
        parth[tid] = v;
    }
    __syncthreads();
    if (tid < 128) a2[tid] = relu_(hb2[tid] + parth[tid] + parth[tid + 128] + parth[tid + 256] + parth[tid + 384]);
    __syncthreads();
    if (tid < 6) {
        const float4* Hr = (const float4*)(H3 + tid * 128);
        float v = hb3[tid];
        for (int i = 0; i < 32; ++i) {
            float4 h4 = Hr[i];
            v += h4.x * a2[i*4] + h4.y * a2[i*4+1] + h4.z * a2[i*4+2] + h4.w * a2[i*4+3];
        }
        out[b * 6 + tid] = v;
    }
}

extern "C" void kernel_launch(void* const* d_in, const int* in_sizes, int n_in,
                              void* d_out, int out_size, void* d_ws, size_t ws_size,
                              hipStream_t stream) {
    const float* x   = (const float*)d_in[0];
    const float* c1w = (const float*)d_in[1];
    const float* c1b = (const float*)d_in[2];
    const float* c2w = (const float*)d_in[3];
    const float* c2b = (const float*)d_in[4];
    const float* c3w = (const float*)d_in[5];
    const float* c3b = (const float*)d_in[6];
    const float* vew = (const float*)d_in[7];
    const float* veb = (const float*)d_in[8];
    const float* t1w = (const float*)d_in[9];
    const float* t1b = (const float*)d_in[10];
    const float* t2w = (const float*)d_in[11];
    const float* t2b = (const float*)d_in[12];
    const float* aiw = (const float*)d_in[13];
    const float* aib = (const float*)d_in[14];
    const float* aow = (const float*)d_in[15];
    const float* aob = (const float*)d_in[16];
    const float* l1g = (const float*)d_in[17];
    const float* l1bb= (const float*)d_in[18];
    const float* l2g = (const float*)d_in[19];
    const float* l2bb= (const float*)d_in[20];
    const float* f1w = (const float*)d_in[21];
    const float* f1b = (const float*)d_in[22];
    const float* f2w = (const float*)d_in[23];
    const float* f2b = (const float*)d_in[24];
    const float* h1w = (const float*)d_in[25];
    const float* h1b = (const float*)d_in[26];
    const float* h2w = (const float*)d_in[27];
    const float* h2b = (const float*)d_in[28];
    const float* h3w = (const float*)d_in[29];
    const float* h3b = (const float*)d_in[30];
    const float* nodes = (const float*)d_in[31];
    const float* edges = (const float*)d_in[32];

    float* W = (float*)d_ws;
    float* h1     = W + 32768;         // 984064
    float* h2     = W + 1016832;       // 460800
    float* h3     = W + 1477632;       // 460800
    float* minout = W + 1938432;       // 98304
    float* cost   = W + 2097152;       // 4194304

    // cost pass (16384 blocks) split across the three conv kernels as grid appendices
    const int nc1 = 5461, nc2 = 5461, nc3 = 5462;
    k_conv1<<<C1_BLOCKS + nc1, 256, 0, stream>>>(x, c1w, c1b, h1, edges, cost, minout, 0);
    k_conv2<<<C2_BLOCKS + nc2, 256, 0, stream>>>(h1, c2w, c2b, h2, edges, cost, minout, nc1);
    k_conv3<<<C3_BLOCKS + nc3, 256, 0, stream>>>(h2, c3w, c3b, h3, edges, cost, minout, nc1 + nc2);
    k_tail<<<BB, 1024, 0, stream>>>(x, h3, vew, veb, cost, nodes, minout,
                                    t1w, t1b, t2w, t2b,
                                    aiw, aib, aow, aob, l1g, l1bb, l2g, l2bb,
                                    f1w, f1b, f2w, f2b, h1w, h1b, h2w, h2b, h3w, h3b,
                                    (float*)d_out);
}